// Round 1
// baseline (96.170 us; speedup 1.0000x reference)
//
#include <hip/hip_runtime.h>

// AverageSpanExtractor: out[b,n,:] = mask[b,n] * mean(seq[b, start:end, :])
// B=8, S=2048, D=512, N=1024, width in [1,20].
// One 128-thread block per span; thread t owns float4 #t of the D=512 row.

#define DV4 128  // D / 4

__global__ __launch_bounds__(128) void span_avg_kernel(
    const float4* __restrict__ seq,   // [B, S, D/4]
    const int*    __restrict__ spans, // [B, N, 2] (start, exclusive end)
    const int*    __restrict__ msk,   // [B, N]
    float4*       __restrict__ out,   // [B, N, D/4]
    int S, int N)
{
    const int n = blockIdx.x;
    const int b = blockIdx.y;
    const int sid = b * N + n;

    const int start = spans[2 * sid];
    const int end   = spans[2 * sid + 1];   // exclusive
    const int width = end - start;

    const int t = threadIdx.x;              // 0..127
    const float4* row = seq + ((size_t)b * S + (size_t)start) * DV4 + t;

    float4 acc = make_float4(0.f, 0.f, 0.f, 0.f);
    for (int w = 0; w < width; ++w) {
        float4 v = row[(size_t)w * DV4];
        acc.x += v.x; acc.y += v.y; acc.z += v.z; acc.w += v.w;
    }

    const float scale = (width > 0) ? ((float)msk[sid] / (float)width) : 0.f;
    acc.x *= scale; acc.y *= scale; acc.z *= scale; acc.w *= scale;

    out[(size_t)sid * DV4 + t] = acc;
}

extern "C" void kernel_launch(void* const* d_in, const int* in_sizes, int n_in,
                              void* d_out, int out_size, void* d_ws, size_t ws_size,
                              hipStream_t stream) {
    const float* seq  = (const float*)d_in[0];   // [B,S,D] fp32
    const int*   sp   = (const int*)d_in[1];     // [B,N,2] int
    const int*   mask = (const int*)d_in[2];     // [B,N] int
    float*       out  = (float*)d_out;           // [B,N,D] fp32

    const int B = 8, S = 2048, N = 1024;
    // Sanity-independent: derive from sizes where possible.
    // in_sizes[2] == B*N, in_sizes[0] == B*S*D with D=512.

    dim3 grid(N, B);
    dim3 block(128);
    span_avg_kernel<<<grid, block, 0, stream>>>(
        (const float4*)seq, sp, mask, (float4*)out, S, N);
}

// Round 2
// 86.261 us; speedup vs baseline: 1.1149x; 1.1149x over previous
//
#include <hip/hip_runtime.h>

// AverageSpanExtractor: out[b,n,:] = mask[b,n] * mean(seq[b, start:end, :])
// B=8, S=2048, D=512, N=1024, width in [1,20].
//
// One 128-thread block per span; thread t owns float4 #t of the D=512 row.
// Round 2 changes vs round 1:
//  - XCD-affine swizzle: b = blockIdx.x & 7 so each XCD's L2 caches only its
//    batch's 4 MB slice of seq (was: every XCD touched all 32 MB -> thrash).
//  - Unroll-by-4 with 4 independent accumulators: 4 loads in flight per
//    s_waitcnt instead of a serial load->wait->add chain per row.

#define DV4 128  // D / 4
#define BATCH 8
#define NSPAN 1024
#define SEQ_S 2048

__global__ __launch_bounds__(128) void span_avg_kernel(
    const float4* __restrict__ seq,   // [B, S, D/4]
    const int*    __restrict__ spans, // [B, N, 2] (start, exclusive end)
    const int*    __restrict__ msk,   // [B, N]
    float4*       __restrict__ out)   // [B, N, D/4]
{
    const int blk = blockIdx.x;       // 0..8191
    const int b = blk & (BATCH - 1);  // XCD-affine: b == XCD id (round-robin)
    const int n = blk >> 3;
    const int sid = b * NSPAN + n;

    const int start = spans[2 * sid];
    const int end   = spans[2 * sid + 1];   // exclusive
    const int width = end - start;          // 1..20 guaranteed

    const int t = threadIdx.x;              // 0..127
    const float4* row = seq + ((size_t)b * SEQ_S + (size_t)start) * DV4 + t;

    float4 a0 = make_float4(0.f, 0.f, 0.f, 0.f);
    float4 a1 = a0, a2 = a0, a3 = a0;

    int w = 0;
    for (; w + 4 <= width; w += 4) {
        float4 v0 = row[(size_t)(w + 0) * DV4];
        float4 v1 = row[(size_t)(w + 1) * DV4];
        float4 v2 = row[(size_t)(w + 2) * DV4];
        float4 v3 = row[(size_t)(w + 3) * DV4];
        a0.x += v0.x; a0.y += v0.y; a0.z += v0.z; a0.w += v0.w;
        a1.x += v1.x; a1.y += v1.y; a1.z += v1.z; a1.w += v1.w;
        a2.x += v2.x; a2.y += v2.y; a2.z += v2.z; a2.w += v2.w;
        a3.x += v3.x; a3.y += v3.y; a3.z += v3.z; a3.w += v3.w;
    }
    // tail (0..3 rows)
    for (; w < width; ++w) {
        float4 v = row[(size_t)w * DV4];
        a0.x += v.x; a0.y += v.y; a0.z += v.z; a0.w += v.w;
    }

    float4 acc;
    acc.x = (a0.x + a1.x) + (a2.x + a3.x);
    acc.y = (a0.y + a1.y) + (a2.y + a3.y);
    acc.z = (a0.z + a1.z) + (a2.z + a3.z);
    acc.w = (a0.w + a1.w) + (a2.w + a3.w);

    const float scale = (float)msk[sid] / (float)width;
    acc.x *= scale; acc.y *= scale; acc.z *= scale; acc.w *= scale;

    out[(size_t)sid * DV4 + t] = acc;
}

extern "C" void kernel_launch(void* const* d_in, const int* in_sizes, int n_in,
                              void* d_out, int out_size, void* d_ws, size_t ws_size,
                              hipStream_t stream) {
    const float* seq  = (const float*)d_in[0];   // [B,S,D] fp32
    const int*   sp   = (const int*)d_in[1];     // [B,N,2] int
    const int*   mask = (const int*)d_in[2];     // [B,N] int
    float*       out  = (float*)d_out;           // [B,N,D] fp32

    dim3 grid(BATCH * NSPAN);
    dim3 block(128);
    span_avg_kernel<<<grid, block, 0, stream>>>(
        (const float4*)seq, sp, mask, (float4*)out);
}